// Round 15
// baseline (212.879 us; speedup 1.0000x reference)
//
#include <hip/hip_runtime.h>
#include <hip/hip_fp16.h>
#include <hip/hip_cooperative_groups.h>
#include <cstdint>

namespace cg = cooperative_groups;

#define BATCH 512
#define CIN   64
#define HH    32
#define WW    64
#define HW    2048
#define C1    32
#define C2    16
#define C3    8
#define C4    4
#define NOUT  256
#define KFC   8192
#define NODES 128
#define KS    16
#define GF_SIZE (BATCH * NODES * CIN)

typedef __attribute__((ext_vector_type(8))) short bfrag;
typedef __attribute__((ext_vector_type(4))) float ffrag;

__device__ __forceinline__ ushort bf_trunc(float f) { return (ushort)(__float_as_uint(f) >> 16); }
__device__ __forceinline__ float  bf_truncf(float f) { return __uint_as_float(__float_as_uint(f) & 0xffff0000u); }
__device__ __forceinline__ ushort f2bf(float f) {
  uint32_t u = __float_as_uint(f);
  return (ushort)((u + 0x7fffu + ((u >> 16) & 1u)) >> 16);
}
__device__ __forceinline__ uint32_t pack2(float a, float b) {
  return (uint32_t)f2bf(a) | ((uint32_t)f2bf(b) << 16);
}
__device__ __forceinline__ uint32_t packhi2(float a, float b) {
  return (uint32_t)bf_trunc(a) | ((uint32_t)bf_trunc(b) << 16);
}
__device__ __forceinline__ ushort f2h(float f) { return __half_as_ushort(__float2half_rn(f)); }
__device__ __forceinline__ uint32_t packh2(float a, float b) {
  return (uint32_t)f2h(a) | ((uint32_t)f2h(b) << 16);
}
__device__ __forceinline__ float h2f(uint32_t u) { return __half2float(__ushort_as_half((ushort)u)); }
__device__ __forceinline__ float bf2f(ushort u) { return __uint_as_float(((uint32_t)u) << 16); }

__device__ __forceinline__ bfrag ld_frag4(const uint32_t* tp) {
  union { uint32_t u[4]; bfrag b; } c;
  c.u[0] = tp[0]; c.u[1] = tp[1]; c.u[2] = tp[2]; c.u[3] = tp[3];
  return c.b;
}

// ===========================================================================
// MEGA: all 4 stages in one persistent cooperative kernel, grid.sync between.
// Phase 0: xpose+conv1 (4096 tiles) + cvt_fcw (1024 tiles)
// Phase 1: conv2+3+4 (2048 tiles)    Phase 2: fc (512 tiles)
// Phase 3: coord+gather (16384 tiles)
// LDS = union(tb 33.8 KB, conv234 50.7 KB) = 50688 B -> 3 blocks/CU.
// ===========================================================================
__global__ __launch_bounds__(256) void k_mega(
    const float* __restrict__ x, const float* __restrict__ w11, const float* __restrict__ b11,
    const float* __restrict__ w12, const float* __restrict__ b12,
    const float* __restrict__ w21, const float* __restrict__ b21,
    const float* __restrict__ w22, const float* __restrict__ b22,
    const float* __restrict__ fcw, const float* __restrict__ fcb,
    ushort* __restrict__ fcwh, ushort* __restrict__ fcwl,
    ushort* __restrict__ xt, ushort* __restrict__ h1g, ushort* __restrict__ h4,
    float* __restrict__ zpart, float* __restrict__ out)
{
  __shared__ __align__(16) char smem[50688];
  cg::grid_group gg = cg::this_grid();
  const int tid = threadIdx.x;
  const int l   = tid & 63;
  const int wv  = tid >> 6;
  const int lr  = l & 15;
  const int lg  = l >> 4;

  // ---------------- Phase 0: xpose + conv1 + cvt_fcw --------------------
  {
    // W1 fragments (hi/lo -> fp32-grade weights), hoisted across tiles.
    bfrag w1h[2][2], w1l[2][2];
    #pragma unroll
    for (int m = 0; m < 2; ++m)
      #pragma unroll
      for (int ks = 0; ks < 2; ++ks) {
        const float* wp = w11 + (m * 16 + lr) * 64 + ks * 32 + lg * 8;
        #pragma unroll
        for (int e = 0; e < 8; ++e) {
          float v = wp[e];
          w1h[m][ks][e] = (short)bf_trunc(v);
          w1l[m][ks][e] = (short)f2bf(v - bf_truncf(v));
        }
      }
    float bias1[2][4];
    #pragma unroll
    for (int m = 0; m < 2; ++m)
      #pragma unroll
      for (int r = 0; r < 4; ++r) bias1[m][r] = b11[m * 16 + lg * 4 + r];

    uint32_t* tb = (uint32_t*)smem;
    for (int tile = blockIdx.x; tile < 5120; tile += gridDim.x) {
      if (tile >= 4096) {              // cvt_fcw tile
        const int chunk = tile - 4096;
        const int i = (chunk * 256 + tid) * 8;
        const float4 a = *(const float4*)(fcw + i);
        const float4 b = *(const float4*)(fcw + i + 4);
        uint4 hv, lv;
        hv.x = packhi2(a.x, a.y); hv.y = packhi2(a.z, a.w);
        hv.z = packhi2(b.x, b.y); hv.w = packhi2(b.z, b.w);
        lv.x = pack2(a.x - bf_truncf(a.x), a.y - bf_truncf(a.y));
        lv.y = pack2(a.z - bf_truncf(a.z), a.w - bf_truncf(a.w));
        lv.z = pack2(b.x - bf_truncf(b.x), b.y - bf_truncf(b.y));
        lv.w = pack2(b.z - bf_truncf(b.z), b.w - bf_truncf(b.w));
        *(uint4*)(fcwh + i) = hv;
        *(uint4*)(fcwl + i) = lv;
        continue;
      }
      const int b  = tile >> 3;
      const int rg = tile & 7;
      {
        const float* xp = x + (size_t)b * CIN * HW + rg * 256 + tid;
        #pragma unroll
        for (int j = 0; j < 32; ++j) {
          float v0 = xp[(size_t)(2 * j) * HW];
          float v1 = xp[(size_t)(2 * j + 1) * HW];
          tb[tid * 33 + j] = pack2(v0, v1);
        }
      }
      __syncthreads();
      {   // xt: consecutive uint4 per consecutive lane
        ushort* op = xt + ((size_t)b * HW + rg * 256) * CIN;
        #pragma unroll
        for (int k = 0; k < 8; ++k) {
          const int u = k * 256 + tid;
          const int p = u >> 3, q = u & 7;
          uint4 v;
          v.x = tb[p * 33 + q * 4 + 0];
          v.y = tb[p * 33 + q * 4 + 1];
          v.z = tb[p * 33 + q * 4 + 2];
          v.w = tb[p * 33 + q * 4 + 3];
          *(uint4*)(op + (size_t)u * 8) = v;
        }
      }
      // conv1 from staged LDS -> h1 px-major bf16
      #pragma unroll
      for (int i = 0; i < 4; ++i) {
        const int pxl = (wv * 4 + i) * 16 + lr;
        const bfrag f0 = ld_frag4(&tb[pxl * 33 + lg * 4]);
        const bfrag f1 = ld_frag4(&tb[pxl * 33 + 16 + lg * 4]);
        ffrag a0 = {0.f, 0.f, 0.f, 0.f}, a1 = {0.f, 0.f, 0.f, 0.f};
        a0 = __builtin_amdgcn_mfma_f32_16x16x32_bf16(w1h[0][0], f0, a0, 0, 0, 0);
        a0 = __builtin_amdgcn_mfma_f32_16x16x32_bf16(w1l[0][0], f0, a0, 0, 0, 0);
        a0 = __builtin_amdgcn_mfma_f32_16x16x32_bf16(w1h[0][1], f1, a0, 0, 0, 0);
        a0 = __builtin_amdgcn_mfma_f32_16x16x32_bf16(w1l[0][1], f1, a0, 0, 0, 0);
        a1 = __builtin_amdgcn_mfma_f32_16x16x32_bf16(w1h[1][0], f0, a1, 0, 0, 0);
        a1 = __builtin_amdgcn_mfma_f32_16x16x32_bf16(w1l[1][0], f0, a1, 0, 0, 0);
        a1 = __builtin_amdgcn_mfma_f32_16x16x32_bf16(w1h[1][1], f1, a1, 0, 0, 0);
        a1 = __builtin_amdgcn_mfma_f32_16x16x32_bf16(w1l[1][1], f1, a1, 0, 0, 0);
        ushort* hp = h1g + ((size_t)b * HW + rg * 256 + pxl) * C1;
        #pragma unroll
        for (int m = 0; m < 2; ++m) {
          float v0 = fmaxf((m ? a1[0] : a0[0]) + bias1[m][0], 0.f);
          float v1 = fmaxf((m ? a1[1] : a0[1]) + bias1[m][1], 0.f);
          float v2 = fmaxf((m ? a1[2] : a0[2]) + bias1[m][2], 0.f);
          float v3 = fmaxf((m ? a1[3] : a0[3]) + bias1[m][3], 0.f);
          *(uint2*)(hp + m * 16 + lg * 4) = uint2{pack2(v0, v1), pack2(v2, v3)};
        }
      }
      __syncthreads();   // protect tb before next tile overwrites it
    }
  }
  gg.sync();

  // ---------------- Phase 1: conv2 + conv3 + conv4 ----------------------
  for (int tile = blockIdx.x; tile < 2048; tile += gridDim.x) {
    const int bg = tile >> 2;
    const int r0 = (tile & 3) * 8;

    if (tid < 192) {   // pad cols (0,65) of all 12 rows (disjoint from bulk)
      int row = tid >> 4, half = (tid >> 3) & 1, q = tid & 7;
      int cell = row * 66 + (half ? 65 : 0);
      *(uint2*)(smem + (cell << 6) + q * 8) = uint2{0u, 0u};
    }
    {   // h1 rows r0-2..r0+9 -> LDS (swizzled)
      const int px = tid >> 2, q = tid & 3;
      const int colb  = px + 1;
      const int chunk = q ^ ((colb >> 1) & 3);
      #pragma unroll
      for (int ry = 0; ry < 12; ++ry) {
        const int y = r0 - 2 + ry;
        uint4 v = uint4{0u, 0u, 0u, 0u};
        if (y >= 0 && y < HH)
          v = *(const uint4*)(h1g + ((size_t)bg * HW + y * WW + px) * C1 + q * 8);
        *(uint4*)(smem + ((ry * 66 + colb) << 6) + (chunk << 4)) = v;
      }
    }
    __syncthreads();

    bfrag w2h[9], w2l[9];
    #pragma unroll
    for (int t = 0; t < 9; ++t) {
      const float* wp = w12 + lr * 288 + t;
      #pragma unroll
      for (int e = 0; e < 8; ++e) {
        float v = wp[(lg * 8 + e) * 9];
        w2h[t][e] = (short)bf_trunc(v);
        w2l[t][e] = (short)f2bf(v - bf_truncf(v));
      }
    }
    float bias2[4];
    #pragma unroll
    for (int r = 0; r < 4; ++r) bias2[r] = b12[lg * 4 + r];

    uint32_t ph0[10], ph1[10];
    #pragma unroll
    for (int i = 0; i < 10; ++i) {
      const int nt   = wv * 10 + i;
      const int hryo = nt >> 2;
      const int col0 = (nt & 3) << 4;
      ffrag acc = {0.f, 0.f, 0.f, 0.f};
      #pragma unroll
      for (int ky = 0; ky < 3; ++ky) {
        const int row = hryo + ky;
        #pragma unroll
        for (int kx = 0; kx < 3; ++kx) {
          const int colb  = col0 + lr + kx;
          const int chunk = lg ^ ((colb >> 1) & 3);
          const bfrag hv = *(const bfrag*)(smem + ((row * 66 + colb) << 6) + (chunk << 4));
          acc = __builtin_amdgcn_mfma_f32_16x16x32_bf16(w2h[ky * 3 + kx], hv, acc, 0, 0, 0);
          acc = __builtin_amdgcn_mfma_f32_16x16x32_bf16(w2l[ky * 3 + kx], hv, acc, 0, 0, 0);
        }
      }
      ph0[i] = packh2(fmaxf(acc[0] + bias2[0], 0.f), fmaxf(acc[1] + bias2[1], 0.f));
      ph1[i] = packh2(fmaxf(acc[2] + bias2[2], 0.f), fmaxf(acc[3] + bias2[3], 0.f));
    }
    __syncthreads();

    #pragma unroll
    for (int i = 0; i < 10; ++i) {
      const int nt   = wv * 10 + i;
      const int hryo = nt >> 2;
      const int col  = ((nt & 3) << 4) + lr;
      *(uint2*)(smem + ((hryo * 64 + col) << 5) + lg * 8) = uint2{ph0[i], ph1[i]};
    }
    __syncthreads();

    float* h3b = (float*)(smem + 20480);
    for (int p = tid; p < 640; p += 256) {
      const int ry = p >> 6, wc = p & 63;
      const int y  = r0 - 1 + ry;
      float* hd = h3b + (ry * 64 + wc) * 9;
      if (y >= 0 && y < HH) {
        const uint4 ua = *(const uint4*)(smem + ((ry * 64 + wc) << 5));
        const uint4 ub = *(const uint4*)(smem + ((ry * 64 + wc) << 5) + 16);
        uint32_t uw[8] = {ua.x, ua.y, ua.z, ua.w, ub.x, ub.y, ub.z, ub.w};
        float xv[16];
        #pragma unroll
        for (int j = 0; j < 8; ++j) {
          xv[2*j]   = h2f(uw[j] & 0xffffu);
          xv[2*j+1] = h2f(uw[j] >> 16);
        }
        float acc[C3];
        #pragma unroll
        for (int o = 0; o < C3; ++o) acc[o] = b21[o];
        #pragma unroll
        for (int c = 0; c < 16; ++c) {
          float v = xv[c];
          #pragma unroll
          for (int o = 0; o < C3; ++o)
            acc[o] = fmaf(v, w21[o * 16 + c], acc[o]);
        }
        #pragma unroll
        for (int c = 0; c < C3; ++c) hd[c] = fmaxf(acc[c], 0.f);
      } else {
        #pragma unroll
        for (int c = 0; c < C3; ++c) hd[c] = 0.f;
      }
    }
    __syncthreads();

    for (int p = tid; p < 512; p += 256) {
      const int yl = p >> 6, wc = p & 63, ry = yl + 1;
      float acc[C4] = {b22[0], b22[1], b22[2], b22[3]};
      #pragma unroll
      for (int ky = 0; ky < 3; ++ky) {
        #pragma unroll
        for (int kx = 0; kx < 3; ++kx) {
          const int wcc = wc + kx - 1;
          if (wcc < 0 || wcc >= WW) continue;
          const float* hb = h3b + ((ry + ky - 1) * 64 + wcc) * 9;
          const int tap = ky * 3 + kx;
          #pragma unroll
          for (int c = 0; c < C3; ++c) {
            float v = hb[c];
            #pragma unroll
            for (int o = 0; o < C4; ++o)
              acc[o] = fmaf(v, w22[(o * 8 + c) * 9 + tap], acc[o]);
          }
        }
      }
      const size_t base = (size_t)bg * KFC + (r0 + yl) * WW + wc;
      #pragma unroll
      for (int o = 0; o < C4; ++o)
        h4[base + (size_t)o * HW] = f2bf(fmaxf(acc[o], 0.f));
    }
    __syncthreads();   // protect smem before next tile
  }
  gg.sync();

  // ---------------- Phase 2: FC GEMM (A single bf16, B hi/lo) -----------
  for (int tile = blockIdx.x; tile < 512; tile += gridDim.x) {
    const int mb = tile & 7, nb = (tile >> 3) & 3, kb = tile >> 5;
    const int m0 = mb * 64 + (wv >> 1) * 32;
    const int n0 = nb * 64 + (wv & 1) * 32;
    const int k0 = kb * (KFC / KS);
    ffrag acc[2][2] = {};
    #pragma unroll 1
    for (int kc = 0; kc < (KFC / KS) / 32; ++kc) {
      const int k = k0 + kc * 32 + lg * 8;
      bfrag ah[2], bh[2], bl[2];
      #pragma unroll
      for (int t = 0; t < 2; ++t) {
        ah[t] = *(const bfrag*)(h4 + (size_t)(m0 + t * 16 + lr) * KFC + k);
        bh[t] = *(const bfrag*)(fcwh + (size_t)(n0 + t * 16 + lr) * KFC + k);
        bl[t] = *(const bfrag*)(fcwl + (size_t)(n0 + t * 16 + lr) * KFC + k);
      }
      #pragma unroll
      for (int mt = 0; mt < 2; ++mt)
        #pragma unroll
        for (int nt = 0; nt < 2; ++nt) {
          acc[mt][nt] = __builtin_amdgcn_mfma_f32_16x16x32_bf16(ah[mt], bh[nt], acc[mt][nt], 0, 0, 0);
          acc[mt][nt] = __builtin_amdgcn_mfma_f32_16x16x32_bf16(ah[mt], bl[nt], acc[mt][nt], 0, 0, 0);
        }
    }
    #pragma unroll
    for (int mt = 0; mt < 2; ++mt)
      #pragma unroll
      for (int r = 0; r < 4; ++r) {
        const int m = m0 + mt * 16 + lg * 4 + r;
        #pragma unroll
        for (int nt = 0; nt < 2; ++nt)
          zpart[((size_t)kb * BATCH + m) * NOUT + n0 + nt * 16 + lr] = acc[mt][nt][r];
      }
  }
  gg.sync();

  // ---------------- Phase 3: coord + bilinear gather --------------------
  for (int tile = blockIdx.x; tile < 16384; tile += gridDim.x) {
    const int xcd = tile & 7;
    const int j   = tile >> 3;
    const int g   = j & 31;
    const int bg  = (j >> 5) * 8 + xcd;          // XCD grouping (512%8==0)
    const int node = g * 4 + (tid >> 6);

    float val = 0.f;
    if (l < 2 * KS) {
      const int kb = l >> 1, comp = l & 1;
      val = zpart[((size_t)kb * BATCH + bg) * NOUT + node * 2 + comp];
    }
    #pragma unroll
    for (int off = 2; off < 2 * KS; off <<= 1) val += __shfl_xor(val, off);
    const float z0 = __shfl(val, 0) + fcb[node * 2 + 0];
    const float z1 = __shfl(val, 1) + fcb[node * 2 + 1];
    const float ch = 31.f / (1.f + __expf(-3.f * z0));
    const float cw = 63.f / (1.f + __expf(-3.f * z1));

    if (l < 2)
      out[GF_SIZE + (((size_t)bg * NODES + node) << 1) + l] = l ? cw : ch;

    const float chv = fminf(fmaxf(ch, 0.f), 31.f);
    const float cwv = fminf(fmaxf(cw, 0.f), 63.f);
    const float fh = floorf(chv), fw = floorf(cwv);
    const int h0 = (int)fh, h1i = (int)ceilf(chv);
    const int w0 = (int)fw, w1i = (int)ceilf(cwv);
    const float oh = chv - fh, ow = cwv - fw;
    const ushort* xbp = xt + (size_t)bg * HW * CIN + l;
    const float v_lt = bf2f(xbp[(size_t)(h0 * WW + w0) * CIN]);
    const float v_rt = bf2f(xbp[(size_t)(h1i * WW + w0) * CIN]);
    const float v_lb = bf2f(xbp[(size_t)(h0 * WW + w1i) * CIN]);
    const float v_rb = bf2f(xbp[(size_t)(h1i * WW + w1i) * CIN]);
    const float vt = v_lt + oh * (v_rt - v_lt);
    const float vb = v_lb + oh * (v_rb - v_lb);
    out[((size_t)bg * NODES + node) * CIN + l] = vt + ow * (vb - vt);
  }
}

// ===========================================================================
// Legacy fallback path (R14-proven): 4 separate kernels.
// ===========================================================================
__global__ __launch_bounds__(256) void k_front(
    const float* __restrict__ x, const float* __restrict__ w11, const float* __restrict__ b11,
    const float* __restrict__ fcw, ushort* __restrict__ fcwh, ushort* __restrict__ fcwl,
    ushort* __restrict__ xt, ushort* __restrict__ h1g)
{
  if (blockIdx.y >= BATCH) {
    const int chunk = (blockIdx.y - BATCH) * 8 + blockIdx.x;
    const int i = (chunk * 256 + threadIdx.x) * 8;
    const float4 a = *(const float4*)(fcw + i);
    const float4 b = *(const float4*)(fcw + i + 4);
    uint4 hv, lv;
    hv.x = packhi2(a.x, a.y); hv.y = packhi2(a.z, a.w);
    hv.z = packhi2(b.x, b.y); hv.w = packhi2(b.z, b.w);
    lv.x = pack2(a.x - bf_truncf(a.x), a.y - bf_truncf(a.y));
    lv.y = pack2(a.z - bf_truncf(a.z), a.w - bf_truncf(a.w));
    lv.z = pack2(b.x - bf_truncf(b.x), b.y - bf_truncf(b.y));
    lv.w = pack2(b.z - bf_truncf(b.z), b.w - bf_truncf(b.w));
    *(uint4*)(fcwh + i) = hv;
    *(uint4*)(fcwl + i) = lv;
    return;
  }
  __shared__ uint32_t tb[256 * 33];
  const int t  = threadIdx.x;
  const int b  = blockIdx.y;
  const int rg = blockIdx.x;
  {
    const float* xp = x + (size_t)b * CIN * HW + rg * 256 + t;
    #pragma unroll
    for (int j = 0; j < 32; ++j) {
      float v0 = xp[(size_t)(2 * j) * HW];
      float v1 = xp[(size_t)(2 * j + 1) * HW];
      tb[t * 33 + j] = pack2(v0, v1);
    }
  }
  __syncthreads();
  {
    ushort* op = xt + ((size_t)b * HW + rg * 256) * CIN;
    #pragma unroll
    for (int k = 0; k < 8; ++k) {
      const int u = k * 256 + t;
      const int p = u >> 3, q = u & 7;
      uint4 v;
      v.x = tb[p * 33 + q * 4 + 0];
      v.y = tb[p * 33 + q * 4 + 1];
      v.z = tb[p * 33 + q * 4 + 2];
      v.w = tb[p * 33 + q * 4 + 3];
      *(uint4*)(op + (size_t)u * 8) = v;
    }
  }
  const int l  = t & 63;
  const int wv = t >> 6;
  const int lr = l & 15;
  const int lg = l >> 4;
  bfrag w1h[2][2], w1l[2][2];
  #pragma unroll
  for (int m = 0; m < 2; ++m)
    #pragma unroll
    for (int ks = 0; ks < 2; ++ks) {
      const float* wp = w11 + (m * 16 + lr) * 64 + ks * 32 + lg * 8;
      #pragma unroll
      for (int e = 0; e < 8; ++e) {
        float v = wp[e];
        w1h[m][ks][e] = (short)bf_trunc(v);
        w1l[m][ks][e] = (short)f2bf(v - bf_truncf(v));
      }
    }
  float bias1[2][4];
  #pragma unroll
  for (int m = 0; m < 2; ++m)
    #pragma unroll
    for (int r = 0; r < 4; ++r) bias1[m][r] = b11[m * 16 + lg * 4 + r];

  #pragma unroll
  for (int i = 0; i < 4; ++i) {
    const int pxl = (wv * 4 + i) * 16 + lr;
    const bfrag f0 = ld_frag4(&tb[pxl * 33 + lg * 4]);
    const bfrag f1 = ld_frag4(&tb[pxl * 33 + 16 + lg * 4]);
    ffrag a0 = {0.f, 0.f, 0.f, 0.f}, a1 = {0.f, 0.f, 0.f, 0.f};
    a0 = __builtin_amdgcn_mfma_f32_16x16x32_bf16(w1h[0][0], f0, a0, 0, 0, 0);
    a0 = __builtin_amdgcn_mfma_f32_16x16x32_bf16(w1l[0][0], f0, a0, 0, 0, 0);
    a0 = __builtin_amdgcn_mfma_f32_16x16x32_bf16(w1h[0][1], f1, a0, 0, 0, 0);
    a0 = __builtin_amdgcn_mfma_f32_16x16x32_bf16(w1l[0][1], f1, a0, 0, 0, 0);
    a1 = __builtin_amdgcn_mfma_f32_16x16x32_bf16(w1h[1][0], f0, a1, 0, 0, 0);
    a1 = __builtin_amdgcn_mfma_f32_16x16x32_bf16(w1l[1][0], f0, a1, 0, 0, 0);
    a1 = __builtin_amdgcn_mfma_f32_16x16x32_bf16(w1h[1][1], f1, a1, 0, 0, 0);
    a1 = __builtin_amdgcn_mfma_f32_16x16x32_bf16(w1l[1][1], f1, a1, 0, 0, 0);
    ushort* hp = h1g + ((size_t)b * HW + rg * 256 + pxl) * C1;
    #pragma unroll
    for (int m = 0; m < 2; ++m) {
      float v0 = fmaxf((m ? a1[0] : a0[0]) + bias1[m][0], 0.f);
      float v1 = fmaxf((m ? a1[1] : a0[1]) + bias1[m][1], 0.f);
      float v2 = fmaxf((m ? a1[2] : a0[2]) + bias1[m][2], 0.f);
      float v3 = fmaxf((m ? a1[3] : a0[3]) + bias1[m][3], 0.f);
      *(uint2*)(hp + m * 16 + lg * 4) = uint2{pack2(v0, v1), pack2(v2, v3)};
    }
  }
}

__global__ __launch_bounds__(256) void k_conv234(
    const ushort* __restrict__ h1g, const float* __restrict__ w12, const float* __restrict__ b12,
    const float* __restrict__ w21, const float* __restrict__ b21,
    const float* __restrict__ w22, const float* __restrict__ b22,
    ushort* __restrict__ h4, int b0)
{
  __shared__ __align__(16) char smem[12 * 66 * 64];
  const int tid = threadIdx.x;
  const int l   = tid & 63;
  const int wv  = tid >> 6;
  const int lr  = l & 15;
  const int lg  = l >> 4;
  const int r0  = blockIdx.x * 8;
  const int bg  = b0 + blockIdx.y;

  if (tid < 192) {
    int row = tid >> 4, half = (tid >> 3) & 1, q = tid & 7;
    int cell = row * 66 + (half ? 65 : 0);
    *(uint2*)(smem + (cell << 6) + q * 8) = uint2{0u, 0u};
  }
  {
    const int px = tid >> 2, q = tid & 3;
    const int colb  = px + 1;
    const int chunk = q ^ ((colb >> 1) & 3);
    #pragma unroll
    for (int ry = 0; ry < 12; ++ry) {
      const int y = r0 - 2 + ry;
      uint4 v = uint4{0u, 0u, 0u, 0u};
      if (y >= 0 && y < HH)
        v = *(const uint4*)(h1g + ((size_t)bg * HW + y * WW + px) * C1 + q * 8);
      *(uint4*)(smem + ((ry * 66 + colb) << 6) + (chunk << 4)) = v;
    }
  }
  __syncthreads();

  bfrag w2h[9], w2l[9];
  #pragma unroll
  for (int t = 0; t < 9; ++t) {
    const float* wp = w12 + lr * 288 + t;
    #pragma unroll
    for (int e = 0; e < 8; ++e) {
      float v = wp[(lg * 8 + e) * 9];
      w2h[t][e] = (short)bf_trunc(v);
      w2l[t][e] = (short)f2bf(v - bf_truncf(v));
    }
  }
  float bias2[4];
  #pragma unroll
  for (int r = 0; r < 4; ++r) bias2[r] = b12[lg * 4 + r];

  uint32_t ph0[10], ph1[10];
  #pragma unroll
  for (int i = 0; i < 10; ++i) {
    const int nt   = wv * 10 + i;
    const int hryo = nt >> 2;
    const int col0 = (nt & 3) << 4;
    ffrag acc = {0.f, 0.f, 0.f, 0.f};
    #pragma unroll
    for (int ky = 0; ky < 3; ++ky) {
      const int row = hryo + ky;
      #pragma unroll
      for (int kx = 0; kx < 3; ++kx) {
        const int colb  = col0 + lr + kx;
        const int chunk = lg ^ ((colb >> 1) & 3);
        const bfrag hv = *(const bfrag*)(smem + ((row * 66 + colb) << 6) + (chunk << 4));
        acc = __builtin_amdgcn_mfma_f32_16x16x32_bf16(w2h[ky * 3 + kx], hv, acc, 0, 0, 0);
        acc = __builtin_amdgcn_mfma_f32_16x16x32_bf16(w2l[ky * 3 + kx], hv, acc, 0, 0, 0);
      }
    }
    ph0[i] = packh2(fmaxf(acc[0] + bias2[0], 0.f), fmaxf(acc[1] + bias2[1], 0.f));
    ph1[i] = packh2(fmaxf(acc[2] + bias2[2], 0.f), fmaxf(acc[3] + bias2[3], 0.f));
  }
  __syncthreads();
  #pragma unroll
  for (int i = 0; i < 10; ++i) {
    const int nt   = wv * 10 + i;
    const int hryo = nt >> 2;
    const int col  = ((nt & 3) << 4) + lr;
    *(uint2*)(smem + ((hryo * 64 + col) << 5) + lg * 8) = uint2{ph0[i], ph1[i]};
  }
  __syncthreads();

  float* h3b = (float*)(smem + 20480);
  for (int p = tid; p < 640; p += 256) {
    const int ry = p >> 6, wc = p & 63;
    const int y  = r0 - 1 + ry;
    float* hd = h3b + (ry * 64 + wc) * 9;
    if (y >= 0 && y < HH) {
      const uint4 ua = *(const uint4*)(smem + ((ry * 64 + wc) << 5));
      const uint4 ub = *(const uint4*)(smem + ((ry * 64 + wc) << 5) + 16);
      uint32_t uw[8] = {ua.x, ua.y, ua.z, ua.w, ub.x, ub.y, ub.z, ub.w};
      float xv[16];
      #pragma unroll
      for (int j = 0; j < 8; ++j) {
        xv[2*j]   = h2f(uw[j] & 0xffffu);
        xv[2*j+1] = h2f(uw[j] >> 16);
      }
      float acc[C3];
      #pragma unroll
      for (int o = 0; o < C3; ++o) acc[o] = b21[o];
      #pragma unroll
      for (int c = 0; c < 16; ++c) {
        float v = xv[c];
        #pragma unroll
        for (int o = 0; o < C3; ++o)
          acc[o] = fmaf(v, w21[o * 16 + c], acc[o]);
      }
      #pragma unroll
      for (int c = 0; c < C3; ++c) hd[c] = fmaxf(acc[c], 0.f);
    } else {
      #pragma unroll
      for (int c = 0; c < C3; ++c) hd[c] = 0.f;
    }
  }
  __syncthreads();

  for (int p = tid; p < 512; p += 256) {
    const int yl = p >> 6, wc = p & 63, ry = yl + 1;
    float acc[C4] = {b22[0], b22[1], b22[2], b22[3]};
    #pragma unroll
    for (int ky = 0; ky < 3; ++ky) {
      #pragma unroll
      for (int kx = 0; kx < 3; ++kx) {
        const int wcc = wc + kx - 1;
        if (wcc < 0 || wcc >= WW) continue;
        const float* hb = h3b + ((ry + ky - 1) * 64 + wcc) * 9;
        const int tap = ky * 3 + kx;
        #pragma unroll
        for (int c = 0; c < C3; ++c) {
          float v = hb[c];
          #pragma unroll
          for (int o = 0; o < C4; ++o)
            acc[o] = fmaf(v, w22[(o * 8 + c) * 9 + tap], acc[o]);
        }
      }
    }
    const size_t base = (size_t)blockIdx.y * KFC + (r0 + yl) * WW + wc;
    #pragma unroll
    for (int o = 0; o < C4; ++o)
      h4[base + (size_t)o * HW] = f2bf(fmaxf(acc[o], 0.f));
  }
}

__global__ __launch_bounds__(256) void k_fc(
    const ushort* __restrict__ Ap_, const ushort* __restrict__ Bhp,
    const ushort* __restrict__ Blp, float* __restrict__ zpart, int cb)
{
  const int tid = threadIdx.x;
  const int l   = tid & 63;
  const int wv  = tid >> 6;
  const int lr  = l & 15;
  const int lg  = l >> 4;
  const int m0  = blockIdx.x * 64 + (wv >> 1) * 32;
  const int n0  = blockIdx.y * 64 + (wv & 1) * 32;
  const int k0  = blockIdx.z * (KFC / KS);
  ffrag acc[2][2] = {};
  #pragma unroll 1
  for (int kc = 0; kc < (KFC / KS) / 32; ++kc) {
    const int k = k0 + kc * 32 + lg * 8;
    bfrag ah[2], bh[2], bl[2];
    #pragma unroll
    for (int t = 0; t < 2; ++t) {
      int m = m0 + t * 16 + lr; if (m >= cb) m = cb - 1;
      ah[t] = *(const bfrag*)(Ap_ + (size_t)m * KFC + k);
      bh[t] = *(const bfrag*)(Bhp + (size_t)(n0 + t * 16 + lr) * KFC + k);
      bl[t] = *(const bfrag*)(Blp + (size_t)(n0 + t * 16 + lr) * KFC + k);
    }
    #pragma unroll
    for (int mt = 0; mt < 2; ++mt)
      #pragma unroll
      for (int nt = 0; nt < 2; ++nt) {
        acc[mt][nt] = __builtin_amdgcn_mfma_f32_16x16x32_bf16(ah[mt], bh[nt], acc[mt][nt], 0, 0, 0);
        acc[mt][nt] = __builtin_amdgcn_mfma_f32_16x16x32_bf16(ah[mt], bl[nt], acc[mt][nt], 0, 0, 0);
      }
  }
  #pragma unroll
  for (int mt = 0; mt < 2; ++mt)
    #pragma unroll
    for (int r = 0; r < 4; ++r) {
      const int m = m0 + mt * 16 + lg * 4 + r;
      if (m < cb)
        #pragma unroll
        for (int nt = 0; nt < 2; ++nt)
          zpart[((size_t)blockIdx.z * cb + m) * NOUT + n0 + nt * 16 + lr] = acc[mt][nt][r];
    }
}

__global__ __launch_bounds__(256) void k_gather(
    const ushort* __restrict__ xt, const float* __restrict__ zpart,
    const float* __restrict__ fcb, float* __restrict__ out, int cb, int b0)
{
  const int bid = blockIdx.x;
  int bl, g;
  if ((cb & 7) == 0) {
    const int xcd = bid & 7;
    const int j   = bid >> 3;
    g  = j & 31;
    bl = (j >> 5) * 8 + xcd;
  } else {
    bl = bid >> 5;
    g  = bid & 31;
  }
  const int node = g * 4 + (threadIdx.x >> 6);
  const int l    = threadIdx.x & 63;
  const int bg   = b0 + bl;
  float val = 0.f;
  if (l < 2 * KS) {
    const int kb = l >> 1, comp = l & 1;
    val = zpart[((size_t)kb * cb + bl) * NOUT + node * 2 + comp];
  }
  #pragma unroll
  for (int off = 2; off < 2 * KS; off <<= 1) val += __shfl_xor(val, off);
  const float z0 = __shfl(val, 0) + fcb[node * 2 + 0];
  const float z1 = __shfl(val, 1) + fcb[node * 2 + 1];
  const float ch = 31.f / (1.f + __expf(-3.f * z0));
  const float cw = 63.f / (1.f + __expf(-3.f * z1));
  if (l < 2)
    out[GF_SIZE + (((size_t)bg * NODES + node) << 1) + l] = l ? cw : ch;
  const float chv = fminf(fmaxf(ch, 0.f), 31.f);
  const float cwv = fminf(fmaxf(cw, 0.f), 63.f);
  const float fh = floorf(chv), fw = floorf(cwv);
  const int h0 = (int)fh, h1i = (int)ceilf(chv);
  const int w0 = (int)fw, w1i = (int)ceilf(cwv);
  const float oh = chv - fh, ow = cwv - fw;
  const ushort* xbp = xt + (size_t)bg * HW * CIN + l;
  const float v_lt = bf2f(xbp[(size_t)(h0 * WW + w0) * CIN]);
  const float v_rt = bf2f(xbp[(size_t)(h1i * WW + w0) * CIN]);
  const float v_lb = bf2f(xbp[(size_t)(h0 * WW + w1i) * CIN]);
  const float v_rb = bf2f(xbp[(size_t)(h1i * WW + w1i) * CIN]);
  const float vt = v_lt + oh * (v_rt - v_lt);
  const float vb = v_lb + oh * (v_rb - v_lb);
  out[((size_t)bg * NODES + node) * CIN + l] = vt + ow * (vb - vt);
}

// ---------------------------------------------------------------------------
extern "C" void kernel_launch(void* const* d_in, const int* in_sizes, int n_in,
                              void* d_out, int out_size, void* d_ws, size_t ws_size,
                              hipStream_t stream)
{
  (void)in_sizes; (void)n_in; (void)out_size; (void)ws_size;
  const float* x   = (const float*)d_in[0];
  const float* w11 = (const float*)d_in[1];
  const float* b11 = (const float*)d_in[2];
  const float* w12 = (const float*)d_in[3];
  const float* b12 = (const float*)d_in[4];
  const float* w21 = (const float*)d_in[5];
  const float* b21 = (const float*)d_in[6];
  const float* w22 = (const float*)d_in[7];
  const float* b22 = (const float*)d_in[8];
  const float* fcw = (const float*)d_in[9];
  const float* fcb = (const float*)d_in[10];
  float* out = (float*)d_out;
  char* p = (char*)d_ws;

  ushort* xtv  = (ushort*)p;  p += (size_t)BATCH * HW * CIN * 2;   // 134 MB
  ushort* h1v  = (ushort*)p;  p += (size_t)BATCH * HW * C1 * 2;    //  67 MB
  ushort* h4v  = (ushort*)p;  p += (size_t)BATCH * KFC * 2;        // 8.4 MB
  float*  zpv  = (float*)p;   p += (size_t)KS * BATCH * NOUT * 4;  // 33.5 MB
  ushort* fcwh = (ushort*)p;  p += (size_t)NOUT * KFC * 2;         // 4.2 MB
  ushort* fcwl = (ushort*)p;

  // capture-safe host queries (no stream ops)
  int dev = 0;
  hipGetDevice(&dev);
  hipDeviceProp_t prop;
  hipError_t e1 = hipGetDeviceProperties(&prop, dev);
  int maxb = 0;
  hipError_t e2 = hipOccupancyMaxActiveBlocksPerMultiprocessor(&maxb, (const void*)k_mega, 256, 0);
  const bool coop = (e1 == hipSuccess) && (e2 == hipSuccess) &&
                    prop.cooperativeLaunch && maxb >= 1;

  if (coop) {
    int nblk = maxb * prop.multiProcessorCount;
    if (nblk < 1) nblk = 1;
    void* args[] = {
      (void*)&x, (void*)&w11, (void*)&b11, (void*)&w12, (void*)&b12,
      (void*)&w21, (void*)&b21, (void*)&w22, (void*)&b22,
      (void*)&fcw, (void*)&fcb,
      (void*)&fcwh, (void*)&fcwl, (void*)&xtv, (void*)&h1v, (void*)&h4v,
      (void*)&zpv, (void*)&out };
    hipLaunchCooperativeKernel((const void*)k_mega, dim3(nblk), dim3(256),
                               args, 0, stream);
  } else {
    k_front<<<dim3(8, BATCH + 128), 256, 0, stream>>>(x, w11, b11, fcw, fcwh, fcwl,
                                                      xtv, h1v);
    k_conv234<<<dim3(4, BATCH), 256, 0, stream>>>(h1v, w12, b12, w21, b21, w22, b22,
                                                  h4v, 0);
    k_fc<<<dim3(BATCH / 64, 4, KS), 256, 0, stream>>>(h4v, fcwh, fcwl, zpv, BATCH);
    k_gather<<<dim3(BATCH * 32), 256, 0, stream>>>(xtv, zpv, fcb, out, BATCH, 0);
  }
}